// Round 10
// baseline (2104.803 us; speedup 1.0000x reference)
//
#include <hip/hip_runtime.h>
#include <hip/hip_fp16.h>

#define DFEAT 64
#define EPS 1e-12f
#define BPB_C 256        // bins per coarse region
#define MAXC 800         // static LDS cap on region count (2N/256 = 782)
#define QPT 4            // quads per thread -> 4096 records per block
#define LSORT 11520      // static LDS cap on region size (45 KB), >= capA

// ---------------------------------------------------------------------------
// R14 (resubmit; R9 bench was an infra container failure, no data):
// merge fine-sort into the gather + fp16 feature tables.
// R13 post-mortem: both changes hit their predicted counter signatures
// (gather VALUBusy 57->36% from scalarized srcw; build unchanged) but time
// barely moved -> build is INSTRUCTION-THROUGHPUT bound (~20 ops x 8M
// records x 2 stages ~= 400us), gather is L2-miss-path bound on feature
// rows (FETCH 890MB of a 2GB demand).
// Changes:
//   - stageB deleted. sort_gather: one 512-thr block per region does
//     in-LDS counting sort (srcwA -> lsort[11520], 45KB) then the 8-wave
//     per-row gather reads records from LDS. Removes a ~15-op/record
//     global pass + 64MB of srcwB traffic; sort ops overlap other blocks'
//     gather latency. 49KB LDS -> 3 blocks/CU = 24 waves (75%).
//   - features converted once to fp16 in ws (rows 128B): demand 2GB->1GB,
//     better L2 hit. fp16 err 2^-12 << w-pack err 2^-9 -> absmax ~same.
//   - stageA untouched (no attribution for its internals yet).
// ---------------------------------------------------------------------------

__device__ __forceinline__ unsigned pack_src_w(int s, float w) {
    // w uniform [0,1): keep 15 bits (sign-free bf16), round-to-nearest.
    unsigned u = __float_as_uint(w) + 0x8000u;
    return (((u >> 16) & 0x7FFFu) << 17) | (unsigned)s;   // src < 2^17
}
__device__ __forceinline__ int unpack_src(unsigned p) { return (int)(p & 0x1FFFFu); }
__device__ __forceinline__ float unpack_w(unsigned p) {
    return __uint_as_float(((p >> 17) & 0x7FFFu) << 16);
}

__global__ void zero_int_kernel(int* __restrict__ p, int n) {
    int i = blockIdx.x * blockDim.x + threadIdx.x;
    if (i < n) p[i] = 0;
}

// ---- fp32 -> fp16 table conversion (8 elements per thread)
__global__ void cvt_half_kernel(const float* __restrict__ src,
                                __half* __restrict__ dst, int n8) {
    int i = blockIdx.x * blockDim.x + threadIdx.x;
    if (i >= n8) return;
    const float4* s4 = reinterpret_cast<const float4*>(src) + (size_t)i * 2;
    float4 a = s4[0], b = s4[1];
    uint4 o;
    o.x = (unsigned)__half_as_ushort(__float2half_rn(a.x)) |
          ((unsigned)__half_as_ushort(__float2half_rn(a.y)) << 16);
    o.y = (unsigned)__half_as_ushort(__float2half_rn(a.z)) |
          ((unsigned)__half_as_ushort(__float2half_rn(a.w)) << 16);
    o.z = (unsigned)__half_as_ushort(__float2half_rn(b.x)) |
          ((unsigned)__half_as_ushort(__float2half_rn(b.y)) << 16);
    o.w = (unsigned)__half_as_ushort(__float2half_rn(b.z)) |
          ((unsigned)__half_as_ushort(__float2half_rn(b.w)) << 16);
    reinterpret_cast<uint4*>(dst)[i] = o;
}

// ---- stage A: partition into slack coarse regions (unchanged from R13).
__global__ __launch_bounds__(256, 6) void stageA_kernel(
        const int* __restrict__ src_ui,
        const int* __restrict__ dst_ui,
        const float* __restrict__ norm_ui,
        const int* __restrict__ src_iu,
        const int* __restrict__ dst_iu,
        const float* __restrict__ norm_iu,
        int* __restrict__ cursorC,
        unsigned* __restrict__ srcwA,
        unsigned char* __restrict__ binA,
        int n_edges, int n_nodes, int nbC, int capA) {
    __shared__ int cnt[MAXC];
    __shared__ int basearr[MAXC];
    __shared__ unsigned binstash[256 * QPT * 4];   // 16 KB: bin|rank<<18
    const int tid = threadIdx.x;
    const long long total = 2LL * n_edges;
    const long long qbase = (long long)blockIdx.x * (256 * QPT);

    for (int c = tid; c < nbC; c += 256) cnt[c] = 0;
    __syncthreads();

    // pass 1: compute bins once, rank via returning atomic, stash both
    for (int k = 0; k < QPT; ++k) {
        const int lq = k * 256 + tid;
        long long q = qbase + lq;
        long long g0 = q << 2;
        const int sidx = lq * 4;
        if (g0 >= total) continue;
        if (g0 + 3 < total && (g0 + 3 < n_edges || g0 >= n_edges)) {
            const bool iu = (g0 >= n_edges);
            long long e0 = iu ? (g0 - n_edges) : g0;
            int4 d = *reinterpret_cast<const int4*>((iu ? dst_iu : dst_ui) + e0);
            int boff = iu ? n_nodes : 0;
            int b0 = d.x + boff, b1 = d.y + boff, b2 = d.z + boff, b3 = d.w + boff;
            int r0 = atomicAdd(&cnt[b0 >> 8], 1);
            int r1 = atomicAdd(&cnt[b1 >> 8], 1);
            int r2 = atomicAdd(&cnt[b2 >> 8], 1);
            int r3 = atomicAdd(&cnt[b3 >> 8], 1);
            binstash[sidx + 0] = (unsigned)b0 | ((unsigned)r0 << 18);
            binstash[sidx + 1] = (unsigned)b1 | ((unsigned)r1 << 18);
            binstash[sidx + 2] = (unsigned)b2 | ((unsigned)r2 << 18);
            binstash[sidx + 3] = (unsigned)b3 | ((unsigned)r3 << 18);
        } else {
            for (long long g = g0; g < g0 + 4 && g < total; ++g) {
                int bin = (g < n_edges) ? dst_ui[g]
                                        : n_nodes + dst_iu[g - n_edges];
                int rk = atomicAdd(&cnt[bin >> 8], 1);
                binstash[sidx + (int)(g - g0)] = (unsigned)bin | ((unsigned)rk << 18);
            }
        }
    }
    __syncthreads();

    // reserve runs (region-relative offsets; regions have ~12% slack)
    for (int c = tid; c < nbC; c += 256) {
        int n = cnt[c];
        basearr[c] = (n > 0) ? atomicAdd(&cursorC[c], n) : 0;
    }
    __syncthreads();

    // pass 2: place records -- atomic-free
    auto place = [&](unsigned st, int s, float w) {
        int bin  = (int)(st & 0x3FFFFu);
        int rank = (int)(st >> 18);
        int bu = bin >> 8;
        int pos = basearr[bu] + rank;
        if (pos < capA) {            // statistically impossible overflow guard
            long long slot = (long long)bu * capA + pos;
            srcwA[slot] = pack_src_w(s, w);
            binA[slot] = (unsigned char)(bin & 255);
        }
    };
    for (int k = 0; k < QPT; ++k) {
        const int lq = k * 256 + tid;
        long long q = qbase + lq;
        long long g0 = q << 2;
        const int sidx = lq * 4;
        if (g0 >= total) continue;
        if (g0 + 3 < total && (g0 + 3 < n_edges || g0 >= n_edges)) {
            const bool iu = (g0 >= n_edges);
            long long e0 = iu ? (g0 - n_edges) : g0;
            int4 s = *reinterpret_cast<const int4*>((iu ? src_iu : src_ui) + e0);
            float4 w = *reinterpret_cast<const float4*>((iu ? norm_iu : norm_ui) + e0);
            place(binstash[sidx + 0], s.x, w.x);
            place(binstash[sidx + 1], s.y, w.y);
            place(binstash[sidx + 2], s.z, w.z);
            place(binstash[sidx + 3], s.w, w.w);
        } else {
            for (long long g = g0; g < g0 + 4 && g < total; ++g) {
                int s; float w;
                if (g < n_edges) { s = src_ui[g]; w = norm_ui[g]; }
                else             { long long e = g - n_edges; s = src_iu[e]; w = norm_iu[e]; }
                place(binstash[sidx + (int)(g - g0)], s, w);
            }
        }
    }
}

// ---- merged fine-sort + gather: one block per region.
// Phases: LDS histogram -> 256-bin scan -> scatter srcwA into bin-sorted
// lsort (LDS) -> 8-wave per-row register gather from LDS with fp16
// feature rows, fused L2-normalize + coalesced store.
__global__ __launch_bounds__(512, 6) void sort_gather_kernel(
        const __half* __restrict__ userH,
        const __half* __restrict__ itemH,
        const int* __restrict__ cursorC,
        const unsigned* __restrict__ srcwA,
        const unsigned char* __restrict__ binA,
        float* __restrict__ out, int n_nodes, int capA) {
    __shared__ unsigned lsort[LSORT];       // 45 KB
    __shared__ int cnt[BPB_C];
    __shared__ int cnt2[BPB_C];
    __shared__ int rowptr[BPB_C + 1];
    __shared__ int wtot[4];
    const int tid = threadIdx.x;
    const int lane = tid & 63;
    const int wid = tid >> 6;               // 0..7
    const int c = blockIdx.x;
    int m = cursorC[c];
    if (m > capA) m = capA;
    const long long base = (long long)c * capA;

    if (tid < BPB_C) { cnt[tid] = 0; cnt2[tid] = 0; }
    __syncthreads();

    // phase 1: histogram of local bins (quad binA reads)
    for (int i = tid * 4; i < m; i += 2048) {
        if (i + 3 < m) {
            uchar4 b = *reinterpret_cast<const uchar4*>(binA + base + i);
            atomicAdd(&cnt[(int)b.x], 1);
            atomicAdd(&cnt[(int)b.y], 1);
            atomicAdd(&cnt[(int)b.z], 1);
            atomicAdd(&cnt[(int)b.w], 1);
        } else {
            for (int k = i; k < m; ++k) atomicAdd(&cnt[(int)binA[base + k]], 1);
        }
    }
    __syncthreads();

    // phase 2: exclusive scan of 256 bins (first 4 waves)
    int v = 0, sc = 0;
    if (tid < BPB_C) {
        v = cnt[tid];
        sc = v;
        #pragma unroll
        for (int off = 1; off < 64; off <<= 1) {
            int y = __shfl_up(sc, off, 64);
            if (lane >= off) sc += y;
        }
        if (lane == 63) wtot[wid] = sc;
    }
    __syncthreads();
    if (tid < BPB_C) {
        int add = 0;
        for (int w = 0; w < wid; ++w) add += wtot[w];
        rowptr[tid] = add + sc - v;
        if (tid == BPB_C - 1) rowptr[BPB_C] = add + sc;
    }
    __syncthreads();

    // phase 3: scatter into bin-sorted LDS order
    for (int i = tid * 4; i < m; i += 2048) {
        if (i + 3 < m) {
            uint4 sv = *reinterpret_cast<const uint4*>(srcwA + base + i);
            uchar4 b = *reinterpret_cast<const uchar4*>(binA + base + i);
            int p0 = rowptr[(int)b.x] + atomicAdd(&cnt2[(int)b.x], 1);
            lsort[p0] = sv.x;
            int p1 = rowptr[(int)b.y] + atomicAdd(&cnt2[(int)b.y], 1);
            lsort[p1] = sv.y;
            int p2 = rowptr[(int)b.z] + atomicAdd(&cnt2[(int)b.z], 1);
            lsort[p2] = sv.z;
            int p3 = rowptr[(int)b.w] + atomicAdd(&cnt2[(int)b.w], 1);
            lsort[p3] = sv.w;
        } else {
            for (int k = i; k < m; ++k) {
                int b = (int)binA[base + k];
                int pos = rowptr[b] + atomicAdd(&cnt2[b], 1);
                lsort[pos] = srcwA[base + k];
            }
        }
    }
    __syncthreads();

    // phase 4: per-row register gather (fp16 rows) + fused normalize + store
    const int n_bins = 2 * n_nodes;
    for (int rr = wid; rr < BPB_C; rr += 8) {
        int bg = c * BPB_C + rr;
        if (bg >= n_bins) break;
        const __half* feat = (bg < n_nodes) ? userH : itemH;
        int js = rowptr[rr];
        int je = rowptr[rr + 1];
        float acc = 0.f;
        int j = js;
        for (; j + 8 <= je; j += 8) {
            unsigned sv[8];
            #pragma unroll
            for (int k = 0; k < 8; ++k) sv[k] = lsort[j + k];
            float fv[8];
            #pragma unroll
            for (int k = 0; k < 8; ++k)
                fv[k] = __half2float(feat[(long long)unpack_src(sv[k]) * DFEAT + lane]);
            #pragma unroll
            for (int k = 0; k < 8; ++k) acc += unpack_w(sv[k]) * fv[k];
        }
        for (; j < je; ++j) {
            unsigned s = lsort[j];
            acc += unpack_w(s) *
                   __half2float(feat[(long long)unpack_src(s) * DFEAT + lane]);
        }
        float ss = acc * acc;
        #pragma unroll
        for (int o = 32; o > 0; o >>= 1) ss += __shfl_xor(ss, o, 64);
        float scale = 1.0f / fmaxf(sqrtf(ss), EPS);
        // out rows [0,N) = user_h <- bins [N,2N); rows [N,2N) = item_h <- [0,N)
        int out_row = (bg < n_nodes) ? (bg + n_nodes) : (bg - n_nodes);
        out[(long long)out_row * DFEAT + lane] = acc * scale;
    }
}

// ---------------------------------------------------------------------------
// Fallback atomic path (proven in R3) if ws_size / shape limits are exceeded.
// ---------------------------------------------------------------------------

__global__ void zero_f32_kernel(float* __restrict__ p, int n4) {
    int i = blockIdx.x * blockDim.x + threadIdx.x;
    if (i < n4) reinterpret_cast<float4*>(p)[i] = make_float4(0.f, 0.f, 0.f, 0.f);
}

__global__ void scatter_edges_kernel(const float* __restrict__ user_feat,
                                     const float* __restrict__ item_feat,
                                     const float* __restrict__ norm_ui,
                                     const float* __restrict__ norm_iu,
                                     const int* __restrict__ src_ui,
                                     const int* __restrict__ dst_ui,
                                     const int* __restrict__ src_iu,
                                     const int* __restrict__ dst_iu,
                                     float* __restrict__ user_acc,
                                     float* __restrict__ item_acc,
                                     int n_edges) {
    long long idx = (long long)blockIdx.x * blockDim.x + threadIdx.x;
    int e = (int)(idx >> 6);
    int d = (int)(idx & 63);
    if (e < n_edges) {
        int s = src_ui[e];
        int t = dst_ui[e];
        atomicAdd(&item_acc[(long long)t * DFEAT + d],
                  norm_ui[e] * user_feat[(long long)s * DFEAT + d]);
    } else {
        e -= n_edges;
        if (e < n_edges) {
            int s = src_iu[e];
            int t = dst_iu[e];
            atomicAdd(&user_acc[(long long)t * DFEAT + d],
                      norm_iu[e] * item_feat[(long long)s * DFEAT + d]);
        }
    }
}

__global__ void normalize_rows_kernel(float* __restrict__ buf, int n_rows) {
    int gid = blockIdx.x * blockDim.x + threadIdx.x;
    int row = gid >> 6;
    int lane = gid & 63;
    if (row >= n_rows) return;
    long long off = (long long)row * DFEAT + lane;
    float x = buf[off];
    float ss = x * x;
    #pragma unroll
    for (int o = 32; o > 0; o >>= 1) ss += __shfl_xor(ss, o, 64);
    float scale = 1.0f / fmaxf(sqrtf(ss), EPS);
    buf[off] = x * scale;
}

extern "C" void kernel_launch(void* const* d_in, const int* in_sizes, int n_in,
                              void* d_out, int out_size, void* d_ws, size_t ws_size,
                              hipStream_t stream) {
    const float* user_feat = (const float*)d_in[0];
    const float* item_feat = (const float*)d_in[1];
    const float* norm_ui   = (const float*)d_in[2];
    const float* norm_iu   = (const float*)d_in[3];
    const int* src_ui = (const int*)d_in[4];
    const int* dst_ui = (const int*)d_in[5];
    const int* src_iu = (const int*)d_in[6];
    const int* dst_iu = (const int*)d_in[7];

    const int n_nodes = in_sizes[0] / DFEAT;        // 100000 (in_sizes = ELEMENT counts)
    const int n_edges = in_sizes[4];                // 4000000
    const int n_bins  = 2 * n_nodes;                // 200000
    const int nbC     = (n_bins + BPB_C - 1) / BPB_C;   // 782
    const long long total = 2LL * n_edges;          // 8M records

    // region capacity: mean + 12.5% slack (~12 sigma for Poisson ~10K), x16
    const long long mean_per_region = total / (nbC > 0 ? nbC : 1);
    long long capA_ll = (mean_per_region + mean_per_region / 8 + 127) & ~15LL;
    if (capA_ll < 256) capA_ll = 256;
    const int capA = (int)capA_ll;

    // ws layout: cursorC[nbC] | userH[n*64 fp16] | itemH[n*64 fp16] (~25.7MB)
    // d_out (n_bins*DFEAT*4 = 51.2MB) stages srcwA[nbC*capA] + binA[nbC*capA]
    // (~45MB; both dead before sort_gather writes d_out rows).
    // NOTE: d_out capacity derived from SHAPE (out_size is in elements).
    auto align256 = [](size_t x) { return (x + 255) & ~(size_t)255; };
    const size_t o_curC  = 0;
    const size_t o_uH    = align256(o_curC + (size_t)nbC * 4);
    const size_t o_iH    = align256(o_uH + (size_t)n_nodes * DFEAT * 2);
    const size_t ws_need = o_iH + (size_t)n_nodes * DFEAT * 2;
    const size_t out_bytes = (size_t)n_bins * DFEAT * sizeof(float);
    const size_t out_need  = (size_t)nbC * capA * 5;   // srcwA (4B) + binA (1B)

    if (nbC <= MAXC && n_nodes <= (1 << 17) && capA <= LSORT &&
        ws_size >= ws_need && out_bytes >= out_need &&
        ((size_t)n_nodes * DFEAT) % 8 == 0) {
        int* cursorC    = (int*)((char*)d_ws + o_curC);
        __half* userH   = (__half*)((char*)d_ws + o_uH);
        __half* itemH   = (__half*)((char*)d_ws + o_iH);
        unsigned* srcwA      = (unsigned*)d_out;
        unsigned char* binA  = (unsigned char*)d_out + (size_t)nbC * capA * 4;

        const long long rpb = 256LL * QPT * 4;          // 4096 records/block
        const int pblocks = (int)((total + rpb - 1) / rpb);   // 1954
        const int n8 = (int)((size_t)n_nodes * DFEAT / 8);    // 800000

        // 1) zero region cursors (ws poisoned every call)
        zero_int_kernel<<<(nbC + 255) / 256, 256, 0, stream>>>(cursorC, nbC);
        // 2) convert feature tables to fp16 (gather demand 2GB -> 1GB)
        cvt_half_kernel<<<(n8 + 255) / 256, 256, 0, stream>>>(user_feat, userH, n8);
        cvt_half_kernel<<<(n8 + 255) / 256, 256, 0, stream>>>(item_feat, itemH, n8);
        // 3) stage A: partition into slack coarse regions
        stageA_kernel<<<pblocks, 256, 0, stream>>>(
            src_ui, dst_ui, norm_ui, src_iu, dst_iu, norm_iu,
            cursorC, srcwA, binA, n_edges, n_nodes, nbC, capA);
        // 4) merged in-LDS fine sort + per-row gather + normalize
        sort_gather_kernel<<<nbC, 512, 0, stream>>>(
            userH, itemH, cursorC, srcwA, binA, (float*)d_out, n_nodes, capA);
    } else {
        // Fallback: atomic accumulation directly in d_out (R3 version).
        float* user_acc = (float*)d_out;
        float* item_acc = user_acc + (size_t)n_nodes * DFEAT;
        const long long out_elems = (long long)n_bins * DFEAT;
        const int n4 = (int)(out_elems / 4);
        zero_f32_kernel<<<(n4 + 255) / 256, 256, 0, stream>>>(user_acc, n4);
        const long long total_threads = 2LL * n_edges * DFEAT;
        scatter_edges_kernel<<<(int)((total_threads + 255) / 256), 256, 0, stream>>>(
            user_feat, item_feat, norm_ui, norm_iu,
            src_ui, dst_ui, src_iu, dst_iu, user_acc, item_acc, n_edges);
        const long long norm_threads = (long long)n_bins * DFEAT;
        normalize_rows_kernel<<<(int)((norm_threads + 255) / 256), 256, 0, stream>>>(
            user_acc, n_bins);
    }
}

// Round 12
// 710.111 us; speedup vs baseline: 2.9640x; 2.9640x over previous
//
#include <hip/hip_runtime.h>

#define DFEAT 64
#define EPS 1e-12f
#define BPB_C 256        // bins per coarse region
#define MAXC 800         // static LDS cap on region count (2N/256 = 782)
#define QPT 4            // quads per thread -> 4096 records per block
#define LSORT 11648      // static LDS cap on region size (45.5 KB), >= capA

// ---------------------------------------------------------------------------
// R16: R14's merged sort+gather, race-fixed.
// R15 post-mortem (FAILED, absmax 0.527): srcwA/binA were staged in d_out;
// sort_gather reads them (phases 1/3) AND writes output rows to d_out
// (phase 4) -> cross-block race (block X's output overwrites block Y's
// unread staging). R11-R13 were safe only because their gather read ws.
// Fix: stage srcwA+binA in ws (45.5MB <= ws's proven ~52MB; R7's guard
// arithmetic: its fast path required cap>=6653 -> ws >= 1563*6653*5).
// fp16 tables dropped (don't fit alongside; was a confounded 2nd variable)
// -> features read fp32 from inputs as in R13. d_out untouched until
// phase-4 output stores: zero aliasing.
// Core theory (R13 post-mortem): build is INSTRUCTION-THROUGHPUT bound
// (~20 ops x 8M records per stage); deleting stageB's global pass saves
// ~190us + 64MB traffic, sort ops hide under other blocks' gather latency.
// ---------------------------------------------------------------------------

__device__ __forceinline__ unsigned pack_src_w(int s, float w) {
    // w uniform [0,1): keep 15 bits (sign-free bf16), round-to-nearest.
    unsigned u = __float_as_uint(w) + 0x8000u;
    return (((u >> 16) & 0x7FFFu) << 17) | (unsigned)s;   // src < 2^17
}
__device__ __forceinline__ int unpack_src(unsigned p) { return (int)(p & 0x1FFFFu); }
__device__ __forceinline__ float unpack_w(unsigned p) {
    return __uint_as_float(((p >> 17) & 0x7FFFu) << 16);
}

__global__ void zero_int_kernel(int* __restrict__ p, int n) {
    int i = blockIdx.x * blockDim.x + threadIdx.x;
    if (i < n) p[i] = 0;
}

// ---- stage A: partition into slack coarse regions (R13-proven).
__global__ __launch_bounds__(256, 6) void stageA_kernel(
        const int* __restrict__ src_ui,
        const int* __restrict__ dst_ui,
        const float* __restrict__ norm_ui,
        const int* __restrict__ src_iu,
        const int* __restrict__ dst_iu,
        const float* __restrict__ norm_iu,
        int* __restrict__ cursorC,
        unsigned* __restrict__ srcwA,
        unsigned char* __restrict__ binA,
        int n_edges, int n_nodes, int nbC, int capA) {
    __shared__ int cnt[MAXC];
    __shared__ int basearr[MAXC];
    __shared__ unsigned binstash[256 * QPT * 4];   // 16 KB: bin|rank<<18
    const int tid = threadIdx.x;
    const long long total = 2LL * n_edges;
    const long long qbase = (long long)blockIdx.x * (256 * QPT);

    for (int c = tid; c < nbC; c += 256) cnt[c] = 0;
    __syncthreads();

    // pass 1: compute bins once, rank via returning atomic, stash both
    for (int k = 0; k < QPT; ++k) {
        const int lq = k * 256 + tid;
        long long q = qbase + lq;
        long long g0 = q << 2;
        const int sidx = lq * 4;
        if (g0 >= total) continue;
        if (g0 + 3 < total && (g0 + 3 < n_edges || g0 >= n_edges)) {
            const bool iu = (g0 >= n_edges);
            long long e0 = iu ? (g0 - n_edges) : g0;
            int4 d = *reinterpret_cast<const int4*>((iu ? dst_iu : dst_ui) + e0);
            int boff = iu ? n_nodes : 0;
            int b0 = d.x + boff, b1 = d.y + boff, b2 = d.z + boff, b3 = d.w + boff;
            int r0 = atomicAdd(&cnt[b0 >> 8], 1);
            int r1 = atomicAdd(&cnt[b1 >> 8], 1);
            int r2 = atomicAdd(&cnt[b2 >> 8], 1);
            int r3 = atomicAdd(&cnt[b3 >> 8], 1);
            binstash[sidx + 0] = (unsigned)b0 | ((unsigned)r0 << 18);
            binstash[sidx + 1] = (unsigned)b1 | ((unsigned)r1 << 18);
            binstash[sidx + 2] = (unsigned)b2 | ((unsigned)r2 << 18);
            binstash[sidx + 3] = (unsigned)b3 | ((unsigned)r3 << 18);
        } else {
            for (long long g = g0; g < g0 + 4 && g < total; ++g) {
                int bin = (g < n_edges) ? dst_ui[g]
                                        : n_nodes + dst_iu[g - n_edges];
                int rk = atomicAdd(&cnt[bin >> 8], 1);
                binstash[sidx + (int)(g - g0)] = (unsigned)bin | ((unsigned)rk << 18);
            }
        }
    }
    __syncthreads();

    // reserve runs (region-relative offsets; regions have ~12% slack)
    for (int c = tid; c < nbC; c += 256) {
        int n = cnt[c];
        basearr[c] = (n > 0) ? atomicAdd(&cursorC[c], n) : 0;
    }
    __syncthreads();

    // pass 2: place records -- atomic-free
    auto place = [&](unsigned st, int s, float w) {
        int bin  = (int)(st & 0x3FFFFu);
        int rank = (int)(st >> 18);
        int bu = bin >> 8;
        int pos = basearr[bu] + rank;
        if (pos < capA) {            // statistically impossible overflow guard
            long long slot = (long long)bu * capA + pos;
            srcwA[slot] = pack_src_w(s, w);
            binA[slot] = (unsigned char)(bin & 255);
        }
    };
    for (int k = 0; k < QPT; ++k) {
        const int lq = k * 256 + tid;
        long long q = qbase + lq;
        long long g0 = q << 2;
        const int sidx = lq * 4;
        if (g0 >= total) continue;
        if (g0 + 3 < total && (g0 + 3 < n_edges || g0 >= n_edges)) {
            const bool iu = (g0 >= n_edges);
            long long e0 = iu ? (g0 - n_edges) : g0;
            int4 s = *reinterpret_cast<const int4*>((iu ? src_iu : src_ui) + e0);
            float4 w = *reinterpret_cast<const float4*>((iu ? norm_iu : norm_ui) + e0);
            place(binstash[sidx + 0], s.x, w.x);
            place(binstash[sidx + 1], s.y, w.y);
            place(binstash[sidx + 2], s.z, w.z);
            place(binstash[sidx + 3], s.w, w.w);
        } else {
            for (long long g = g0; g < g0 + 4 && g < total; ++g) {
                int s; float w;
                if (g < n_edges) { s = src_ui[g]; w = norm_ui[g]; }
                else             { long long e = g - n_edges; s = src_iu[e]; w = norm_iu[e]; }
                place(binstash[sidx + (int)(g - g0)], s, w);
            }
        }
    }
}

// ---- merged fine-sort + gather: one block per region.
// Phases: LDS histogram -> 256-bin scan -> scatter srcwA into bin-sorted
// lsort (LDS) -> 8-wave per-row register gather (fp32 rows), fused
// L2-normalize + coalesced store. Reads ws only; writes d_out only.
__global__ __launch_bounds__(512, 6) void sort_gather_kernel(
        const float* __restrict__ user_feat,
        const float* __restrict__ item_feat,
        const int* __restrict__ cursorC,
        const unsigned* __restrict__ srcwA,
        const unsigned char* __restrict__ binA,
        float* __restrict__ out, int n_nodes, int capA) {
    __shared__ unsigned lsort[LSORT];       // 45.5 KB
    __shared__ int cnt[BPB_C];
    __shared__ int cnt2[BPB_C];
    __shared__ int rowptr[BPB_C + 1];
    __shared__ int wtot[4];
    const int tid = threadIdx.x;
    const int lane = tid & 63;
    const int wid = tid >> 6;               // 0..7
    const int c = blockIdx.x;
    int m = cursorC[c];
    if (m > capA) m = capA;
    const long long base = (long long)c * capA;

    if (tid < BPB_C) { cnt[tid] = 0; cnt2[tid] = 0; }
    __syncthreads();

    // phase 1: histogram of local bins (quad binA reads)
    for (int i = tid * 4; i < m; i += 2048) {
        if (i + 3 < m) {
            uchar4 b = *reinterpret_cast<const uchar4*>(binA + base + i);
            atomicAdd(&cnt[(int)b.x], 1);
            atomicAdd(&cnt[(int)b.y], 1);
            atomicAdd(&cnt[(int)b.z], 1);
            atomicAdd(&cnt[(int)b.w], 1);
        } else {
            for (int k = i; k < m; ++k) atomicAdd(&cnt[(int)binA[base + k]], 1);
        }
    }
    __syncthreads();

    // phase 2: exclusive scan of 256 bins (first 4 waves)
    int v = 0, sc = 0;
    if (tid < BPB_C) {
        v = cnt[tid];
        sc = v;
        #pragma unroll
        for (int off = 1; off < 64; off <<= 1) {
            int y = __shfl_up(sc, off, 64);
            if (lane >= off) sc += y;
        }
        if (lane == 63) wtot[wid] = sc;
    }
    __syncthreads();
    if (tid < BPB_C) {
        int add = 0;
        for (int w = 0; w < wid; ++w) add += wtot[w];
        rowptr[tid] = add + sc - v;
        if (tid == BPB_C - 1) rowptr[BPB_C] = add + sc;
    }
    __syncthreads();

    // phase 3: scatter into bin-sorted LDS order
    for (int i = tid * 4; i < m; i += 2048) {
        if (i + 3 < m) {
            uint4 sv = *reinterpret_cast<const uint4*>(srcwA + base + i);
            uchar4 b = *reinterpret_cast<const uchar4*>(binA + base + i);
            int p0 = rowptr[(int)b.x] + atomicAdd(&cnt2[(int)b.x], 1);
            lsort[p0] = sv.x;
            int p1 = rowptr[(int)b.y] + atomicAdd(&cnt2[(int)b.y], 1);
            lsort[p1] = sv.y;
            int p2 = rowptr[(int)b.z] + atomicAdd(&cnt2[(int)b.z], 1);
            lsort[p2] = sv.z;
            int p3 = rowptr[(int)b.w] + atomicAdd(&cnt2[(int)b.w], 1);
            lsort[p3] = sv.w;
        } else {
            for (int k = i; k < m; ++k) {
                int b = (int)binA[base + k];
                int pos = rowptr[b] + atomicAdd(&cnt2[b], 1);
                lsort[pos] = srcwA[base + k];
            }
        }
    }
    __syncthreads();

    // phase 4: per-row register gather + fused normalize + store
    const int n_bins = 2 * n_nodes;
    for (int rr = wid; rr < BPB_C; rr += 8) {
        int bg = c * BPB_C + rr;
        if (bg >= n_bins) break;
        const float* feat = (bg < n_nodes) ? user_feat : item_feat;
        int js = rowptr[rr];
        int je = rowptr[rr + 1];
        float acc = 0.f;
        int j = js;
        for (; j + 8 <= je; j += 8) {
            unsigned sv[8];
            #pragma unroll
            for (int k = 0; k < 8; ++k) sv[k] = lsort[j + k];
            float fv[8];
            #pragma unroll
            for (int k = 0; k < 8; ++k)
                fv[k] = feat[(long long)unpack_src(sv[k]) * DFEAT + lane];
            #pragma unroll
            for (int k = 0; k < 8; ++k) acc += unpack_w(sv[k]) * fv[k];
        }
        for (; j < je; ++j) {
            unsigned s = lsort[j];
            acc += unpack_w(s) * feat[(long long)unpack_src(s) * DFEAT + lane];
        }
        float ss = acc * acc;
        #pragma unroll
        for (int o = 32; o > 0; o >>= 1) ss += __shfl_xor(ss, o, 64);
        float scale = 1.0f / fmaxf(sqrtf(ss), EPS);
        // out rows [0,N) = user_h <- bins [N,2N); rows [N,2N) = item_h <- [0,N)
        int out_row = (bg < n_nodes) ? (bg + n_nodes) : (bg - n_nodes);
        out[(long long)out_row * DFEAT + lane] = acc * scale;
    }
}

// ---------------------------------------------------------------------------
// Fallback atomic path (proven in R3) if ws_size / shape limits are exceeded.
// ---------------------------------------------------------------------------

__global__ void zero_f32_kernel(float* __restrict__ p, int n4) {
    int i = blockIdx.x * blockDim.x + threadIdx.x;
    if (i < n4) reinterpret_cast<float4*>(p)[i] = make_float4(0.f, 0.f, 0.f, 0.f);
}

__global__ void scatter_edges_kernel(const float* __restrict__ user_feat,
                                     const float* __restrict__ item_feat,
                                     const float* __restrict__ norm_ui,
                                     const float* __restrict__ norm_iu,
                                     const int* __restrict__ src_ui,
                                     const int* __restrict__ dst_ui,
                                     const int* __restrict__ src_iu,
                                     const int* __restrict__ dst_iu,
                                     float* __restrict__ user_acc,
                                     float* __restrict__ item_acc,
                                     int n_edges) {
    long long idx = (long long)blockIdx.x * blockDim.x + threadIdx.x;
    int e = (int)(idx >> 6);
    int d = (int)(idx & 63);
    if (e < n_edges) {
        int s = src_ui[e];
        int t = dst_ui[e];
        atomicAdd(&item_acc[(long long)t * DFEAT + d],
                  norm_ui[e] * user_feat[(long long)s * DFEAT + d]);
    } else {
        e -= n_edges;
        if (e < n_edges) {
            int s = src_iu[e];
            int t = dst_iu[e];
            atomicAdd(&user_acc[(long long)t * DFEAT + d],
                      norm_iu[e] * item_feat[(long long)s * DFEAT + d]);
        }
    }
}

__global__ void normalize_rows_kernel(float* __restrict__ buf, int n_rows) {
    int gid = blockIdx.x * blockDim.x + threadIdx.x;
    int row = gid >> 6;
    int lane = gid & 63;
    if (row >= n_rows) return;
    long long off = (long long)row * DFEAT + lane;
    float x = buf[off];
    float ss = x * x;
    #pragma unroll
    for (int o = 32; o > 0; o >>= 1) ss += __shfl_xor(ss, o, 64);
    float scale = 1.0f / fmaxf(sqrtf(ss), EPS);
    buf[off] = x * scale;
}

extern "C" void kernel_launch(void* const* d_in, const int* in_sizes, int n_in,
                              void* d_out, int out_size, void* d_ws, size_t ws_size,
                              hipStream_t stream) {
    const float* user_feat = (const float*)d_in[0];
    const float* item_feat = (const float*)d_in[1];
    const float* norm_ui   = (const float*)d_in[2];
    const float* norm_iu   = (const float*)d_in[3];
    const int* src_ui = (const int*)d_in[4];
    const int* dst_ui = (const int*)d_in[5];
    const int* src_iu = (const int*)d_in[6];
    const int* dst_iu = (const int*)d_in[7];

    const int n_nodes = in_sizes[0] / DFEAT;        // 100000 (in_sizes = ELEMENT counts)
    const int n_edges = in_sizes[4];                // 4000000
    const int n_bins  = 2 * n_nodes;                // 200000
    const int nbC     = (n_bins + BPB_C - 1) / BPB_C;   // 782
    const long long total = 2LL * n_edges;          // 8M records

    // region capacity: mean + 12.5% slack (~12 sigma for Poisson ~10K), x16
    // For the bench shape: capA = (10230 + 1278 + 127) & ~15 = 11632 <= LSORT.
    const long long mean_per_region = total / (nbC > 0 ? nbC : 1);
    long long capA_ll = (mean_per_region + mean_per_region / 8 + 127) & ~15LL;
    if (capA_ll < 256) capA_ll = 256;
    const int capA = (int)capA_ll;

    // ws layout: cursorC[nbC] | srcwA[nbC*capA u32] | binA[nbC*capA u8]
    // = ~45.5MB <= ws's proven ~52MB (R7 fast path required >=52MB).
    // d_out is written ONLY by sort_gather phase 4 (no staging aliasing --
    // R15's race fix).
    auto align256 = [](size_t x) { return (x + 255) & ~(size_t)255; };
    const size_t o_curC  = 0;
    const size_t o_srcwA = align256(o_curC + (size_t)nbC * 4);
    const size_t o_binA  = align256(o_srcwA + (size_t)nbC * capA * 4);
    const size_t ws_need = o_binA + (size_t)nbC * capA;

    if (nbC <= MAXC && n_nodes <= (1 << 17) && capA <= LSORT &&
        ws_size >= ws_need) {
        int* cursorC        = (int*)((char*)d_ws + o_curC);
        unsigned* srcwA     = (unsigned*)((char*)d_ws + o_srcwA);
        unsigned char* binA = (unsigned char*)((char*)d_ws + o_binA);

        const long long rpb = 256LL * QPT * 4;          // 4096 records/block
        const int pblocks = (int)((total + rpb - 1) / rpb);   // 1954

        // 1) zero region cursors (ws poisoned every call)
        zero_int_kernel<<<(nbC + 255) / 256, 256, 0, stream>>>(cursorC, nbC);
        // 2) stage A: partition into slack coarse regions
        stageA_kernel<<<pblocks, 256, 0, stream>>>(
            src_ui, dst_ui, norm_ui, src_iu, dst_iu, norm_iu,
            cursorC, srcwA, binA, n_edges, n_nodes, nbC, capA);
        // 3) merged in-LDS fine sort + per-row gather + normalize
        sort_gather_kernel<<<nbC, 512, 0, stream>>>(
            user_feat, item_feat, cursorC, srcwA, binA,
            (float*)d_out, n_nodes, capA);
    } else {
        // Fallback: atomic accumulation directly in d_out (R3 version).
        float* user_acc = (float*)d_out;
        float* item_acc = user_acc + (size_t)n_nodes * DFEAT;
        const long long out_elems = (long long)n_bins * DFEAT;
        const int n4 = (int)(out_elems / 4);
        zero_f32_kernel<<<(n4 + 255) / 256, 256, 0, stream>>>(user_acc, n4);
        const long long total_threads = 2LL * n_edges * DFEAT;
        scatter_edges_kernel<<<(int)((total_threads + 255) / 256), 256, 0, stream>>>(
            user_feat, item_feat, norm_ui, norm_iu,
            src_ui, dst_ui, src_iu, dst_iu, user_acc, item_acc, n_edges);
        const long long norm_threads = (long long)n_bins * DFEAT;
        normalize_rows_kernel<<<(int)((norm_threads + 255) / 256), 256, 0, stream>>>(
            user_acc, n_bins);
    }
}

// Round 13
// 644.863 us; speedup vs baseline: 3.2640x; 1.1012x over previous
//
#include <hip/hip_runtime.h>

#define DFEAT 64
#define EPS 1e-12f
#define BPB_C 256        // bins per coarse region
#define MAXC 800         // static LDS cap on region count (2N/256 = 782)
#define QPT 4            // quads per thread -> 4096 records per block
#define CAPB 11648       // static LDS cap on stageB region size (>= capA)

// ---------------------------------------------------------------------------
// R17: R13 revert (best proven, 651us) + wide-load gather.
// R16 post-mortem (710us): merged sort+gather lost more to occupancy
// (78->45%, 50KB LDS, all 782 blocks resident -> no cross-block phase
// overlap) + 2.4M lsort bank conflicts than it saved by deleting stageB's
// global pass. Dedicated zero-LDS gather at 8 blocks/CU wins -> revert.
// New reading of R13 counters: fp32 tables (51.2MB) fit L3 entirely, so
// FETCH 890MB@249us = 3.6TB/s is the L2-miss->L3 path, and it exactly
// accounts for gather dur. Test: is it BW-bound or concurrency-bound?
// Gather restructure: (group=lane/16) x (sub=lane%16); each float4 load
// instruction fetches 4 DIFFERENT rows (1KB/instr), acc = per-lane float4,
// cross-group shfl_xor(16,32) reduce, 16-lane float4 store. 16 records per
// iter with 4 loads (was 16 loads of 4B) -> 4x MLP per issue slot.
// Predicted: FETCH ~890MB unchanged; concurrency-limited -> gather ~170us;
// hard L3 ceiling -> ~245us and next lever must cut bytes.
// ---------------------------------------------------------------------------

__device__ __forceinline__ unsigned pack_src_w(int s, float w) {
    // w uniform [0,1): keep 15 bits (sign-free bf16), round-to-nearest.
    unsigned u = __float_as_uint(w) + 0x8000u;
    return (((u >> 16) & 0x7FFFu) << 17) | (unsigned)s;   // src < 2^17
}
__device__ __forceinline__ int unpack_src(unsigned p) { return (int)(p & 0x1FFFFu); }
__device__ __forceinline__ float unpack_w(unsigned p) {
    return __uint_as_float(((p >> 17) & 0x7FFFu) << 16);
}

__global__ void zero_int_kernel(int* __restrict__ p, int n) {
    int i = blockIdx.x * blockDim.x + threadIdx.x;
    if (i < n) p[i] = 0;
}

// ---- stage A: partition into slack coarse regions (R13-proven).
// Pass 1: quad dst loads; returning LDS hist atomic gives per-block rank;
//         stash (bin | rank<<18) in LDS.
// Pass 2: quad src/norm loads; pos = basearr + rank; NO atomics.
__global__ __launch_bounds__(256, 6) void stageA_kernel(
        const int* __restrict__ src_ui,
        const int* __restrict__ dst_ui,
        const float* __restrict__ norm_ui,
        const int* __restrict__ src_iu,
        const int* __restrict__ dst_iu,
        const float* __restrict__ norm_iu,
        int* __restrict__ cursorC,
        unsigned* __restrict__ srcwA,
        unsigned char* __restrict__ binA,
        int n_edges, int n_nodes, int nbC, int capA) {
    __shared__ int cnt[MAXC];
    __shared__ int basearr[MAXC];
    __shared__ unsigned binstash[256 * QPT * 4];   // 16 KB: bin|rank<<18
    const int tid = threadIdx.x;
    const long long total = 2LL * n_edges;
    const long long qbase = (long long)blockIdx.x * (256 * QPT);

    for (int c = tid; c < nbC; c += 256) cnt[c] = 0;
    __syncthreads();

    // pass 1: compute bins once, rank via returning atomic, stash both
    for (int k = 0; k < QPT; ++k) {
        const int lq = k * 256 + tid;
        long long q = qbase + lq;
        long long g0 = q << 2;
        const int sidx = lq * 4;
        if (g0 >= total) continue;
        if (g0 + 3 < total && (g0 + 3 < n_edges || g0 >= n_edges)) {
            const bool iu = (g0 >= n_edges);
            long long e0 = iu ? (g0 - n_edges) : g0;
            int4 d = *reinterpret_cast<const int4*>((iu ? dst_iu : dst_ui) + e0);
            int boff = iu ? n_nodes : 0;
            int b0 = d.x + boff, b1 = d.y + boff, b2 = d.z + boff, b3 = d.w + boff;
            int r0 = atomicAdd(&cnt[b0 >> 8], 1);
            int r1 = atomicAdd(&cnt[b1 >> 8], 1);
            int r2 = atomicAdd(&cnt[b2 >> 8], 1);
            int r3 = atomicAdd(&cnt[b3 >> 8], 1);
            binstash[sidx + 0] = (unsigned)b0 | ((unsigned)r0 << 18);
            binstash[sidx + 1] = (unsigned)b1 | ((unsigned)r1 << 18);
            binstash[sidx + 2] = (unsigned)b2 | ((unsigned)r2 << 18);
            binstash[sidx + 3] = (unsigned)b3 | ((unsigned)r3 << 18);
        } else {
            for (long long g = g0; g < g0 + 4 && g < total; ++g) {
                int bin = (g < n_edges) ? dst_ui[g]
                                        : n_nodes + dst_iu[g - n_edges];
                int rk = atomicAdd(&cnt[bin >> 8], 1);
                binstash[sidx + (int)(g - g0)] = (unsigned)bin | ((unsigned)rk << 18);
            }
        }
    }
    __syncthreads();

    // reserve runs (region-relative offsets; regions have ~12% slack)
    for (int c = tid; c < nbC; c += 256) {
        int n = cnt[c];
        basearr[c] = (n > 0) ? atomicAdd(&cursorC[c], n) : 0;
    }
    __syncthreads();

    // pass 2: place records -- atomic-free
    auto place = [&](unsigned st, int s, float w) {
        int bin  = (int)(st & 0x3FFFFu);
        int rank = (int)(st >> 18);
        int bu = bin >> 8;
        int pos = basearr[bu] + rank;
        if (pos < capA) {            // statistically impossible overflow guard
            long long slot = (long long)bu * capA + pos;
            srcwA[slot] = pack_src_w(s, w);
            binA[slot] = (unsigned char)(bin & 255);
        }
    };
    for (int k = 0; k < QPT; ++k) {
        const int lq = k * 256 + tid;
        long long q = qbase + lq;
        long long g0 = q << 2;
        const int sidx = lq * 4;
        if (g0 >= total) continue;
        if (g0 + 3 < total && (g0 + 3 < n_edges || g0 >= n_edges)) {
            const bool iu = (g0 >= n_edges);
            long long e0 = iu ? (g0 - n_edges) : g0;
            int4 s = *reinterpret_cast<const int4*>((iu ? src_iu : src_ui) + e0);
            float4 w = *reinterpret_cast<const float4*>((iu ? norm_iu : norm_ui) + e0);
            place(binstash[sidx + 0], s.x, w.x);
            place(binstash[sidx + 1], s.y, w.y);
            place(binstash[sidx + 2], s.z, w.z);
            place(binstash[sidx + 3], s.w, w.w);
        } else {
            for (long long g = g0; g < g0 + 4 && g < total; ++g) {
                int s; float w;
                if (g < n_edges) { s = src_ui[g]; w = norm_ui[g]; }
                else             { long long e = g - n_edges; s = src_iu[e]; w = norm_iu[e]; }
                place(binstash[sidx + (int)(g - g0)], s, w);
            }
        }
    }
}

// ---- stage B: per-region counting sort into packed CSR spans (R13-proven).
// Phase 1 stashes rank(u16)+bin(u8); phase 3 scatter is atomic-free.
__global__ __launch_bounds__(512, 8) void stageB_kernel(
        const int* __restrict__ cursorC,
        int* __restrict__ gcur,
        const unsigned* __restrict__ srcwA,
        const unsigned char* __restrict__ binA,
        unsigned* __restrict__ srcwB,
        int* __restrict__ startF,
        int* __restrict__ endF,
        int n_bins, int capA) {
    __shared__ int cnt[BPB_C];
    __shared__ int rp[BPB_C];
    __shared__ int wtot[4];
    __shared__ int sbase;
    __shared__ unsigned short rankL[CAPB];   // 22.75 KB
    __shared__ unsigned char  binL[CAPB];    // 11.4 KB
    const int tid = threadIdx.x;
    const int lane = tid & 63;
    const int wid = tid >> 6;
    const int c = blockIdx.x;
    int m = cursorC[c];
    if (m > capA) m = capA;
    const long long js = (long long)c * capA;

    if (tid < BPB_C) cnt[tid] = 0;
    __syncthreads();

    // phase 1: histogram with rank capture (quad binA reads)
    for (int i = tid * 4; i < m; i += 2048) {
        if (i + 3 < m) {
            uchar4 b = *reinterpret_cast<const uchar4*>(binA + js + i);
            int r0 = atomicAdd(&cnt[(int)b.x], 1);
            int r1 = atomicAdd(&cnt[(int)b.y], 1);
            int r2 = atomicAdd(&cnt[(int)b.z], 1);
            int r3 = atomicAdd(&cnt[(int)b.w], 1);
            rankL[i + 0] = (unsigned short)r0; binL[i + 0] = b.x;
            rankL[i + 1] = (unsigned short)r1; binL[i + 1] = b.y;
            rankL[i + 2] = (unsigned short)r2; binL[i + 2] = b.z;
            rankL[i + 3] = (unsigned short)r3; binL[i + 3] = b.w;
        } else {
            for (int k = i; k < m; ++k) {
                unsigned char bb = binA[js + k];
                int rk = atomicAdd(&cnt[(int)bb], 1);
                rankL[k] = (unsigned short)rk; binL[k] = bb;
            }
        }
    }
    __syncthreads();

    // reserve packed span + exclusive scan of 256 bins (waves 0-3)
    if (tid == 0) sbase = atomicAdd(gcur, m);
    int v = 0, sc = 0;
    if (tid < BPB_C) {
        v = cnt[tid];
        sc = v;
        #pragma unroll
        for (int off = 1; off < 64; off <<= 1) {
            int y = __shfl_up(sc, off, 64);
            if (lane >= off) sc += y;
        }
        if (lane == 63) wtot[wid] = sc;
    }
    __syncthreads();
    if (tid < BPB_C) {
        int add = 0;
        for (int w = 0; w < wid; ++w) add += wtot[w];
        int excl = add + sc - v;
        rp[tid] = excl;
        int bg = c * BPB_C + tid;
        if (bg < n_bins) {
            startF[bg] = sbase + excl;
            endF[bg]   = sbase + excl + v;
        }
    }
    __syncthreads();

    // phase 3: atomic-free scatter into packed span (window stays in L2)
    for (int i = tid * 4; i < m; i += 2048) {
        if (i + 3 < m) {
            uint4 sv = *reinterpret_cast<const uint4*>(srcwA + js + i);
            int p0 = sbase + rp[(int)binL[i + 0]] + (int)rankL[i + 0];
            int p1 = sbase + rp[(int)binL[i + 1]] + (int)rankL[i + 1];
            int p2 = sbase + rp[(int)binL[i + 2]] + (int)rankL[i + 2];
            int p3 = sbase + rp[(int)binL[i + 3]] + (int)rankL[i + 3];
            srcwB[p0] = sv.x;
            srcwB[p1] = sv.y;
            srcwB[p2] = sv.z;
            srcwB[p3] = sv.w;
        } else {
            for (int k = i; k < m; ++k) {
                int pos = sbase + rp[(int)binL[k]] + (int)rankL[k];
                srcwB[pos] = srcwA[js + k];
            }
        }
    }
}

// ---- CSR gather, wide-load form: one output row per wave, zero LDS.
// group g = lane/16 handles record subset; sub = lane%16 owns dims
// [4*sub, 4*sub+3]. Each float4 load instruction fetches 4 different
// feature rows (1KB); acc is per-lane float4; cross-group shfl_xor(16,32)
// reduce; lanes 0-15 do the coalesced float4 store.
__global__ __launch_bounds__(256, 8) void csr_gather_kernel(
    const float* __restrict__ user_feat,
    const float* __restrict__ item_feat,
    const int* __restrict__ startF,
    const int* __restrict__ endF,
    const unsigned* __restrict__ srcw,
    float* __restrict__ out, int n_nodes) {
    const int tid = threadIdx.x;
    const int lane = tid & 63;
    const int wid = tid >> 6;
    const int g = lane >> 4;            // 0..3 row-group
    const int sub = lane & 15;          // 0..15 dim-group (4 dims each)
    const int n_bins = 2 * n_nodes;
    const int r = blockIdx.x * 4 + wid;
    if (r >= n_bins) return;
    const float* feat = (r < n_nodes) ? user_feat : item_feat;
    // row bounds are wave-uniform: pin to SGPRs so srcw loads scalarize.
    const int js = __builtin_amdgcn_readfirstlane(startF[r]);
    const int je = __builtin_amdgcn_readfirstlane(endF[r]);
    float4 acc = make_float4(0.f, 0.f, 0.f, 0.f);
    int j = js;
    for (; j + 16 <= je; j += 16) {
        unsigned sv[16];
        #pragma unroll
        for (int k = 0; k < 16; ++k) sv[k] = srcw[j + k];   // scalar (s_load)
        float4 fv[4];
        #pragma unroll
        for (int q = 0; q < 4; ++q) {
            int rec = q * 4 + g;
            fv[q] = reinterpret_cast<const float4*>(
                        feat + (long long)unpack_src(sv[rec]) * DFEAT)[sub];
        }
        #pragma unroll
        for (int q = 0; q < 4; ++q) {
            float wq = unpack_w(sv[q * 4 + g]);
            acc.x += wq * fv[q].x;
            acc.y += wq * fv[q].y;
            acc.z += wq * fv[q].z;
            acc.w += wq * fv[q].w;
        }
    }
    for (; j + 4 <= je; j += 4) {
        unsigned s = srcw[j + g];
        float4 f = reinterpret_cast<const float4*>(
                       feat + (long long)unpack_src(s) * DFEAT)[sub];
        float wq = unpack_w(s);
        acc.x += wq * f.x; acc.y += wq * f.y;
        acc.z += wq * f.z; acc.w += wq * f.w;
    }
    {
        int rem = je - j;               // 0..3
        if (g < rem) {
            unsigned s = srcw[j + g];
            float4 f = reinterpret_cast<const float4*>(
                           feat + (long long)unpack_src(s) * DFEAT)[sub];
            float wq = unpack_w(s);
            acc.x += wq * f.x; acc.y += wq * f.y;
            acc.z += wq * f.z; acc.w += wq * f.w;
        }
    }
    // cross-group reduce: combine the 4 row-groups' partial sums
    #pragma unroll
    for (int o = 16; o < 64; o <<= 1) {
        acc.x += __shfl_xor(acc.x, o, 64);
        acc.y += __shfl_xor(acc.y, o, 64);
        acc.z += __shfl_xor(acc.z, o, 64);
        acc.w += __shfl_xor(acc.w, o, 64);
    }
    // L2 norm over the 64 dims (16 subs x 4 comps, identical across groups)
    float ss = acc.x * acc.x + acc.y * acc.y + acc.z * acc.z + acc.w * acc.w;
    #pragma unroll
    for (int o = 1; o < 16; o <<= 1) ss += __shfl_xor(ss, o, 64);
    float scale = 1.0f / fmaxf(sqrtf(ss), EPS);
    // out rows [0,N) = user_h <- bins [N,2N); rows [N,2N) = item_h <- bins [0,N)
    int out_row = (r < n_nodes) ? (r + n_nodes) : (r - n_nodes);
    if (g == 0) {
        float4 o4 = make_float4(acc.x * scale, acc.y * scale,
                                acc.z * scale, acc.w * scale);
        reinterpret_cast<float4*>(out + (long long)out_row * DFEAT)[sub] = o4;
    }
}

// ---------------------------------------------------------------------------
// Fallback atomic path (proven in R3) if ws_size / shape limits are exceeded.
// ---------------------------------------------------------------------------

__global__ void zero_f32_kernel(float* __restrict__ p, int n4) {
    int i = blockIdx.x * blockDim.x + threadIdx.x;
    if (i < n4) reinterpret_cast<float4*>(p)[i] = make_float4(0.f, 0.f, 0.f, 0.f);
}

__global__ void scatter_edges_kernel(const float* __restrict__ user_feat,
                                     const float* __restrict__ item_feat,
                                     const float* __restrict__ norm_ui,
                                     const float* __restrict__ norm_iu,
                                     const int* __restrict__ src_ui,
                                     const int* __restrict__ dst_ui,
                                     const int* __restrict__ src_iu,
                                     const int* __restrict__ dst_iu,
                                     float* __restrict__ user_acc,
                                     float* __restrict__ item_acc,
                                     int n_edges) {
    long long idx = (long long)blockIdx.x * blockDim.x + threadIdx.x;
    int e = (int)(idx >> 6);
    int d = (int)(idx & 63);
    if (e < n_edges) {
        int s = src_ui[e];
        int t = dst_ui[e];
        atomicAdd(&item_acc[(long long)t * DFEAT + d],
                  norm_ui[e] * user_feat[(long long)s * DFEAT + d]);
    } else {
        e -= n_edges;
        if (e < n_edges) {
            int s = src_iu[e];
            int t = dst_iu[e];
            atomicAdd(&user_acc[(long long)t * DFEAT + d],
                      norm_iu[e] * item_feat[(long long)s * DFEAT + d]);
        }
    }
}

__global__ void normalize_rows_kernel(float* __restrict__ buf, int n_rows) {
    int gid = blockIdx.x * blockDim.x + threadIdx.x;
    int row = gid >> 6;
    int lane = gid & 63;
    if (row >= n_rows) return;
    long long off = (long long)row * DFEAT + lane;
    float x = buf[off];
    float ss = x * x;
    #pragma unroll
    for (int o = 32; o > 0; o >>= 1) ss += __shfl_xor(ss, o, 64);
    float scale = 1.0f / fmaxf(sqrtf(ss), EPS);
    buf[off] = x * scale;
}

extern "C" void kernel_launch(void* const* d_in, const int* in_sizes, int n_in,
                              void* d_out, int out_size, void* d_ws, size_t ws_size,
                              hipStream_t stream) {
    const float* user_feat = (const float*)d_in[0];
    const float* item_feat = (const float*)d_in[1];
    const float* norm_ui   = (const float*)d_in[2];
    const float* norm_iu   = (const float*)d_in[3];
    const int* src_ui = (const int*)d_in[4];
    const int* dst_ui = (const int*)d_in[5];
    const int* src_iu = (const int*)d_in[6];
    const int* dst_iu = (const int*)d_in[7];

    const int n_nodes = in_sizes[0] / DFEAT;        // 100000 (in_sizes = ELEMENT counts)
    const int n_edges = in_sizes[4];                // 4000000
    const int n_bins  = 2 * n_nodes;                // 200000
    const int nbC     = (n_bins + BPB_C - 1) / BPB_C;   // 782
    const long long total = 2LL * n_edges;          // 8M records

    // region capacity: mean + 12.5% slack (~12 sigma for Poisson ~10K), x16
    // Bench shape: capA = (10230 + 1278 + 127) & ~15 = 11632 <= CAPB 11648.
    const long long mean_per_region = total / (nbC > 0 ? nbC : 1);
    long long capA_ll = (mean_per_region + mean_per_region / 8 + 127) & ~15LL;
    if (capA_ll < 256) capA_ll = 256;
    const int capA = (int)capA_ll;

    // ws layout: cursorC[nbC] | gcur[1] | startF[n_bins] | endF[n_bins]
    //            | srcwB[total]                               (~34 MB)
    // d_out (n_bins*DFEAT*4 = 51.2MB) stages srcwA[nbC*capA] + binA[nbC*capA]
    // (~45.5MB; dead before the gather, which reads only ws, writes d_out).
    // NOTE: d_out capacity derived from SHAPE (out_size is in elements).
    auto align256 = [](size_t x) { return (x + 255) & ~(size_t)255; };
    const size_t o_curC  = 0;
    const size_t o_stF   = align256(o_curC + ((size_t)nbC + 1) * 4);
    const size_t o_enF   = align256(o_stF + (size_t)n_bins * 4);
    const size_t o_srcwB = align256(o_enF + (size_t)n_bins * 4);
    const size_t ws_need = o_srcwB + (size_t)total * 4;
    const size_t out_bytes = (size_t)n_bins * DFEAT * sizeof(float);
    const size_t out_need  = (size_t)nbC * capA * 5;   // srcwA (4B) + binA (1B)

    if (nbC <= MAXC && n_nodes <= (1 << 17) && capA <= CAPB &&
        ws_size >= ws_need && out_bytes >= out_need) {
        int* cursorC    = (int*)((char*)d_ws + o_curC);
        int* gcur       = cursorC + nbC;
        int* startF     = (int*)((char*)d_ws + o_stF);
        int* endF       = (int*)((char*)d_ws + o_enF);
        unsigned* srcwB = (unsigned*)((char*)d_ws + o_srcwB);
        unsigned* srcwA      = (unsigned*)d_out;
        unsigned char* binA  = (unsigned char*)d_out + (size_t)nbC * capA * 4;

        const long long rpb = 256LL * QPT * 4;          // 4096 records/block
        const int pblocks = (int)((total + rpb - 1) / rpb);   // 1954

        // 1) zero region cursors + global cursor (ws poisoned every call)
        zero_int_kernel<<<(nbC + 256) / 256, 256, 0, stream>>>(cursorC, nbC + 1);
        // 2) stage A: partition into slack coarse regions (atomic-free place)
        stageA_kernel<<<pblocks, 256, 0, stream>>>(
            src_ui, dst_ui, norm_ui, src_iu, dst_iu, norm_iu,
            cursorC, srcwA, binA, n_edges, n_nodes, nbC, capA);
        // 3) stage B: per-region counting sort -> packed CSR spans
        stageB_kernel<<<nbC, 512, 0, stream>>>(
            cursorC, gcur, srcwA, binA, srcwB, startF, endF, n_bins, capA);
        // 4) zero-LDS wide-load CSR gather + fused normalize
        csr_gather_kernel<<<(n_bins + 3) / 4, 256, 0, stream>>>(
            user_feat, item_feat, startF, endF, srcwB, (float*)d_out, n_nodes);
    } else {
        // Fallback: atomic accumulation directly in d_out (R3 version).
        float* user_acc = (float*)d_out;
        float* item_acc = user_acc + (size_t)n_nodes * DFEAT;
        const long long out_elems = (long long)n_bins * DFEAT;
        const int n4 = (int)(out_elems / 4);
        zero_f32_kernel<<<(n4 + 255) / 256, 256, 0, stream>>>(user_acc, n4);
        const long long total_threads = 2LL * n_edges * DFEAT;
        scatter_edges_kernel<<<(int)((total_threads + 255) / 256), 256, 0, stream>>>(
            user_feat, item_feat, norm_ui, norm_iu,
            src_ui, dst_ui, src_iu, dst_iu, user_acc, item_acc, n_edges);
        const long long norm_threads = (long long)n_bins * DFEAT;
        normalize_rows_kernel<<<(int)((norm_threads + 255) / 256), 256, 0, stream>>>(
            user_acc, n_bins);
    }
}